// Round 10
// baseline (287.467 us; speedup 1.0000x reference)
//
#include <hip/hip_runtime.h>
#include <hip/hip_bf16.h>

// GNN: 2x GCNConv(128->128) + ReLU, global_mean_pool, MLP head 128->128->1.
// R10: feature-plane split. h matrices (A,B) stored as 4 planes of N x 32 bf16
// (3.2 MB/plane < 4 MiB XCD L2) so aggregate's random per-edge gathers become
// L2-resident: 4 plane-passes, 8 lanes x ushort4 = 64B row per edge per plane.
// deg+compact merged (pads edge lists to x4 with zero-weight no-op entries);
// GEMM epilogues write plane-major (planes align with k-steps, so bf16 GEMM
// A-frags stay contiguous short8); pool reads planes (pooled layout unchanged).

#define CAP 16            // slots per replica
#define NREP 4            // replicas
#define STRIDE 64         // entries per node (NREP*CAP)

typedef __attribute__((ext_vector_type(8))) short short8;
typedef __attribute__((ext_vector_type(4))) float floatx4;

__device__ inline unsigned short f2bf(float f) {
    unsigned int u = __float_as_uint(f);
    u += 0x7FFF + ((u >> 16) & 1);   // RNE
    return (unsigned short)(u >> 16);
}
__device__ inline float bf2f(unsigned short h) {
    return __uint_as_float(((unsigned int)h) << 16);
}

// ---------------- one-pass CSR build (4 replicas) ----------------
__global__ void build_csr(const int* __restrict__ src, const int* __restrict__ dst,
                          const float* __restrict__ ew,
                          int* __restrict__ cnt, int2* __restrict__ csr, int e, int n) {
    int i = blockIdx.x * blockDim.x + threadIdx.x;
    if (i < e) {
        int d = dst[i];
        int r = i & (NREP - 1);
        int pos = atomicAdd(&cnt[(size_t)r * n + d], 1);
        csr[((size_t)d << 6) + (r << 4) + pos] = make_int2(src[i], __float_as_int(ew[i]));
    }
}

// ---- degree + compact replica segments + pad to x4 (zero-weight no-ops) ----
__global__ __launch_bounds__(256) void deg_compact(int* __restrict__ cnt,
        int2* __restrict__ csr, float* __restrict__ dinv, int n) {
    int node = blockIdx.x * 8 + (threadIdx.x >> 5);
    if (node >= n) return;
    int lane = threadIdx.x & 31;
    int c0 = cnt[node];
    int c1 = cnt[(size_t)1 * n + node];
    int c2 = cnt[(size_t)2 * n + node];
    int c3 = cnt[(size_t)3 * n + node];
    int pre[4] = {0, c0, c0 + c1, c0 + c1 + c2};
    int cs[4] = {c0, c1, c2, c3};
    int ctot = c0 + c1 + c2 + c3;
    int cp = (ctot + 3) & ~3;

    int2* b = csr + ((size_t)node << 6);
    int pos = lane & 15;
    int sa = lane >> 4;
    int sb = 2 + (lane >> 4);
    bool va = pos < cs[sa];
    bool vb = pos < cs[sb];
    // all loads before any stores (in-place compaction safety)
    int2 ea = va ? b[lane] : make_int2(0, 0);
    int2 eb = vb ? b[32 + lane] : make_int2(0, 0);
    // weighted degree
    float s = (va ? __int_as_float(ea.y) : 0.0f) + (vb ? __int_as_float(eb.y) : 0.0f);
#pragma unroll
    for (int off = 16; off > 0; off >>= 1) s += __shfl_down(s, off, 32);
    if (va) b[pre[sa] + pos] = ea;
    if (vb) b[pre[sb] + pos] = eb;
    if (lane < cp - ctot) b[ctot + lane] = make_int2(0, 0);   // pad (w=0 no-op)
    if (lane == 0) {
        cnt[node] = cp;
        dinv[node] = rsqrtf(s + 1.0f);   // +1 self-loop
    }
}

// ---------------- fold dinv[src] into stored weights ----------------
__global__ __launch_bounds__(256) void fold_dinv(const int* __restrict__ cnt,
        int2* __restrict__ csr, const float* __restrict__ dinv, int n) {
    int node = blockIdx.x * 8 + (threadIdx.x >> 5);
    if (node >= n) return;
    int lane = threadIdx.x & 31;
    int cp = cnt[node];
    int2* b = csr + ((size_t)node << 6);
    if (lane < cp) {
        int2 e = b[lane];
        e.y = __float_as_int(__int_as_float(e.y) * dinv[e.x]);
        b[lane] = e;
    }
    if (32 + lane < cp) {
        int2 e = b[32 + lane];
        e.y = __float_as_int(__int_as_float(e.y) * dinv[e.x]);
        b[32 + lane] = e;
    }
}

// ------- split-bf16 MFMA GEMM (fp32 input): C = X @ W^T, C bf16 planes -------
#define PW 136
__global__ __launch_bounds__(256) void gemm_f32_nt(const float* __restrict__ X,
        const float* __restrict__ W, unsigned short* __restrict__ C, int M) {
    __shared__ unsigned short whi[128 * PW];
    __shared__ unsigned short wlo[128 * PW];
    const int t = threadIdx.x;
    const size_t Np = (size_t)M * 32;   // plane stride

    {
        int j = t >> 1;
        int c0 = (t & 1) * 64;
        const floatx4* wr = (const floatx4*)(W + (size_t)j * 128 + c0);
        unsigned short* dh = &whi[j * PW + c0];
        unsigned short* dl = &wlo[j * PW + c0];
#pragma unroll
        for (int i = 0; i < 16; ++i) {
            floatx4 v = wr[i];
            ushort4 hv, lv;
            hv.x = f2bf(v.x); lv.x = f2bf(v.x - bf2f(hv.x));
            hv.y = f2bf(v.y); lv.y = f2bf(v.y - bf2f(hv.y));
            hv.z = f2bf(v.z); lv.z = f2bf(v.z - bf2f(hv.z));
            hv.w = f2bf(v.w); lv.w = f2bf(v.w - bf2f(hv.w));
            *(ushort4*)(dh + i * 4) = hv;
            *(ushort4*)(dl + i * 4) = lv;
        }
    }
    __syncthreads();

    const int wave = t >> 6;
    const int lane = t & 63;
    const int q = lane >> 4;
    const int ln = lane & 15;
    const int rowbase = blockIdx.x * 128 + wave * 32;

    floatx4 acc[2][8];
#pragma unroll
    for (int s = 0; s < 2; ++s)
#pragma unroll
        for (int ct = 0; ct < 8; ++ct) acc[s][ct] = (floatx4){0.f, 0.f, 0.f, 0.f};

#pragma unroll
    for (int ks = 0; ks < 4; ++ks) {
        short8 ahi[2], alo[2];
#pragma unroll
        for (int s = 0; s < 2; ++s) {
            int row = rowbase + s * 16 + ln;
            int rowc = (row < M) ? row : (M - 1);
            const floatx4* xr = (const floatx4*)(X + (size_t)rowc * 128 + ks * 32 + q * 8);
            floatx4 x0 = xr[0];
            floatx4 x1 = xr[1];
            unsigned short h, l;
            h = f2bf(x0.x); l = f2bf(x0.x - bf2f(h)); ahi[s][0] = (short)h; alo[s][0] = (short)l;
            h = f2bf(x0.y); l = f2bf(x0.y - bf2f(h)); ahi[s][1] = (short)h; alo[s][1] = (short)l;
            h = f2bf(x0.z); l = f2bf(x0.z - bf2f(h)); ahi[s][2] = (short)h; alo[s][2] = (short)l;
            h = f2bf(x0.w); l = f2bf(x0.w - bf2f(h)); ahi[s][3] = (short)h; alo[s][3] = (short)l;
            h = f2bf(x1.x); l = f2bf(x1.x - bf2f(h)); ahi[s][4] = (short)h; alo[s][4] = (short)l;
            h = f2bf(x1.y); l = f2bf(x1.y - bf2f(h)); ahi[s][5] = (short)h; alo[s][5] = (short)l;
            h = f2bf(x1.z); l = f2bf(x1.z - bf2f(h)); ahi[s][6] = (short)h; alo[s][6] = (short)l;
            h = f2bf(x1.w); l = f2bf(x1.w - bf2f(h)); ahi[s][7] = (short)h; alo[s][7] = (short)l;
        }
#pragma unroll
        for (int ct = 0; ct < 8; ++ct) {
            int lidx = (ct * 16 + ln) * PW + ks * 32 + q * 8;
            short8 bhi = *(const short8*)&whi[lidx];
            short8 blo = *(const short8*)&wlo[lidx];
#pragma unroll
            for (int s = 0; s < 2; ++s) {
                acc[s][ct] = __builtin_amdgcn_mfma_f32_16x16x32_bf16(ahi[s], bhi, acc[s][ct], 0, 0, 0);
                acc[s][ct] = __builtin_amdgcn_mfma_f32_16x16x32_bf16(ahi[s], blo, acc[s][ct], 0, 0, 0);
                acc[s][ct] = __builtin_amdgcn_mfma_f32_16x16x32_bf16(alo[s], bhi, acc[s][ct], 0, 0, 0);
            }
        }
    }

    // col c = ct*16+ln -> plane ct>>1, in-plane col (ct&1)*16+ln
#pragma unroll
    for (int s = 0; s < 2; ++s) {
#pragma unroll
        for (int r = 0; r < 4; ++r) {
            int row = rowbase + s * 16 + q * 4 + r;
            if (row < M) {
#pragma unroll
                for (int ct = 0; ct < 8; ++ct)
                    C[(size_t)(ct >> 1) * Np + (size_t)row * 32 + (ct & 1) * 16 + ln] =
                        f2bf(acc[s][ct][r]);
            }
        }
    }
}

// ---- bf16-input MFMA GEMM: X bf16 planes, W split hi/lo, C bf16 planes ----
__global__ __launch_bounds__(256) void gemm_bf16_nt(const unsigned short* __restrict__ X,
        const float* __restrict__ W, unsigned short* __restrict__ C, int M) {
    __shared__ unsigned short whi[128 * PW];
    __shared__ unsigned short wlo[128 * PW];
    const int t = threadIdx.x;
    const size_t Np = (size_t)M * 32;

    {
        int j = t >> 1;
        int c0 = (t & 1) * 64;
        const floatx4* wr = (const floatx4*)(W + (size_t)j * 128 + c0);
        unsigned short* dh = &whi[j * PW + c0];
        unsigned short* dl = &wlo[j * PW + c0];
#pragma unroll
        for (int i = 0; i < 16; ++i) {
            floatx4 v = wr[i];
            ushort4 hv, lv;
            hv.x = f2bf(v.x); lv.x = f2bf(v.x - bf2f(hv.x));
            hv.y = f2bf(v.y); lv.y = f2bf(v.y - bf2f(hv.y));
            hv.z = f2bf(v.z); lv.z = f2bf(v.z - bf2f(hv.z));
            hv.w = f2bf(v.w); lv.w = f2bf(v.w - bf2f(hv.w));
            *(ushort4*)(dh + i * 4) = hv;
            *(ushort4*)(dl + i * 4) = lv;
        }
    }
    __syncthreads();

    const int wave = t >> 6;
    const int lane = t & 63;
    const int q = lane >> 4;
    const int ln = lane & 15;
    const int rowbase = blockIdx.x * 128 + wave * 32;

    floatx4 acc[2][8];
#pragma unroll
    for (int s = 0; s < 2; ++s)
#pragma unroll
        for (int ct = 0; ct < 8; ++ct) acc[s][ct] = (floatx4){0.f, 0.f, 0.f, 0.f};

#pragma unroll
    for (int ks = 0; ks < 4; ++ks) {
        // plane ks holds feats ks*32..ks*32+31: contiguous short8 at off q*8
        short8 a[2];
#pragma unroll
        for (int s = 0; s < 2; ++s) {
            int row = rowbase + s * 16 + ln;
            int rowc = (row < M) ? row : (M - 1);
            a[s] = *(const short8*)(X + (size_t)ks * Np + (size_t)rowc * 32 + q * 8);
        }
#pragma unroll
        for (int ct = 0; ct < 8; ++ct) {
            int lidx = (ct * 16 + ln) * PW + ks * 32 + q * 8;
            short8 bhi = *(const short8*)&whi[lidx];
            short8 blo = *(const short8*)&wlo[lidx];
#pragma unroll
            for (int s = 0; s < 2; ++s) {
                acc[s][ct] = __builtin_amdgcn_mfma_f32_16x16x32_bf16(a[s], bhi, acc[s][ct], 0, 0, 0);
                acc[s][ct] = __builtin_amdgcn_mfma_f32_16x16x32_bf16(a[s], blo, acc[s][ct], 0, 0, 0);
            }
        }
    }

#pragma unroll
    for (int s = 0; s < 2; ++s) {
#pragma unroll
        for (int r = 0; r < 4; ++r) {
            int row = rowbase + s * 16 + q * 4 + r;
            if (row < M) {
#pragma unroll
                for (int ct = 0; ct < 8; ++ct)
                    C[(size_t)(ct >> 1) * Np + (size_t)row * 32 + (ct & 1) * 16 + ln] =
                        f2bf(acc[s][ct][r]);
            }
        }
    }
}

// ------ aggregate + finalize, plane-pass version ------
// grid = 4*NB; plane = blockIdx.x/NB. Per 32-lane group: one node; lane l
// handles edge subset l>>3 (4 edges/iter), feats (l&7)*4..+3 of plane p.
__global__ __launch_bounds__(256) void aggregate_finalize(
        const unsigned short* __restrict__ h, const unsigned short* __restrict__ hlin,
        const int* __restrict__ cnt, const int2* __restrict__ csr,
        const float* __restrict__ dinv, const float* __restrict__ bias,
        unsigned short* __restrict__ outb, int n, int nb) {
    int p = blockIdx.x / nb;
    int node = (blockIdx.x % nb) * 8 + (threadIdx.x >> 5);
    if (node >= n) return;
    int lane = threadIdx.x & 31;
    int esub = lane >> 3;        // 0..3
    int fl = lane & 7;           // feat quad 0..7
    const size_t Np = (size_t)n * 32;
    const unsigned short* hp = h + (size_t)p * Np;

    float4 acc = make_float4(0.f, 0.f, 0.f, 0.f);
    const int2* b = csr + ((size_t)node << 6);
    int c = cnt[node];           // padded to multiple of 4 (w=0 entries)
    for (int k = 0; k < c; k += 4) {
        int2 e = b[k + esub];    // 8-lane broadcast
        float w = __int_as_float(e.y);
        ushort4 hv = *(const ushort4*)(hp + (size_t)e.x * 32 + fl * 4);
        acc.x += bf2f(hv.x) * w;
        acc.y += bf2f(hv.y) * w;
        acc.z += bf2f(hv.z) * w;
        acc.w += bf2f(hv.w) * w;
    }
    // reduce across the 4 edge subsets (lanes l, l^8, l^16, l^24)
    acc.x += __shfl_xor(acc.x, 8, 32);  acc.y += __shfl_xor(acc.y, 8, 32);
    acc.z += __shfl_xor(acc.z, 8, 32);  acc.w += __shfl_xor(acc.w, 8, 32);
    acc.x += __shfl_xor(acc.x, 16, 32); acc.y += __shfl_xor(acc.y, 16, 32);
    acc.z += __shfl_xor(acc.z, 16, 32); acc.w += __shfl_xor(acc.w, 16, 32);

    if (esub == 0) {   // lanes 0..7 hold the full sums
        float di = dinv[node];
        float sl = di * di;
        ushort4 hs = *(const ushort4*)(hlin + (size_t)p * Np + (size_t)node * 32 + fl * 4);
        float4 b4 = ((const float4*)(bias + p * 32))[fl];
        ushort4 o;
        o.x = f2bf(fmaxf(acc.x * di + bf2f(hs.x) * sl + b4.x, 0.0f));
        o.y = f2bf(fmaxf(acc.y * di + bf2f(hs.y) * sl + b4.y, 0.0f));
        o.z = f2bf(fmaxf(acc.z * di + bf2f(hs.z) * sl + b4.z, 0.0f));
        o.w = f2bf(fmaxf(acc.w * di + bf2f(hs.w) * sl + b4.w, 0.0f));
        *(ushort4*)(outb + (size_t)p * Np + (size_t)node * 32 + fl * 4) = o;
    }
}

// -------- pooling: partial sums over plane-major bf16, boundary-flush --------
#define POOL_BLOCKS 1024
__global__ __launch_bounds__(128) void pool_partial(const unsigned short* __restrict__ h,
        const int* __restrict__ batch, float* __restrict__ pooled, int n) {
    int chunk = (n + POOL_BLOCKS - 1) / POOL_BLOCKS;
    int s = blockIdx.x * chunk;
    if (s >= n) return;
    int e = min(s + chunk, n);
    int j = threadIdx.x;                   // feature j = plane j>>5, off j&31
    const size_t Np = (size_t)n * 32;
    const unsigned short* hp = h + (size_t)(j >> 5) * Np + (j & 31);
    int curg = batch[s];
    float sum = 0.0f;
    for (int i = s; i < e; ++i) {
        int g = batch[i];
        if (g != curg) {
            atomicAdd(&pooled[(size_t)curg * 128 + j], sum);
            sum = 0.0f;
            curg = g;
        }
        sum += bf2f(hp[(size_t)i * 32]);
    }
    atomicAdd(&pooled[(size_t)curg * 128 + j], sum);
}

// ---------------- head MLP ----------------
__global__ __launch_bounds__(128) void head_mlp(const float* __restrict__ pooled,
        const int* __restrict__ batch, int n,
        const float* __restrict__ fW1, const float* __restrict__ fb1,
        const float* __restrict__ fW2, const float* __restrict__ fb2,
        float* __restrict__ out) {
    int g = blockIdx.x;
    int j = threadIdx.x;
    int lo = 0, hi = n;
    while (lo < hi) { int mid = (lo + hi) >> 1; if (batch[mid] < g) lo = mid + 1; else hi = mid; }
    int s = lo;
    hi = n;
    while (lo < hi) { int mid = (lo + hi) >> 1; if (batch[mid] < g + 1) lo = mid + 1; else hi = mid; }
    int cnt = lo - s;
    float scale = 1.0f / fmaxf((float)cnt, 1.0f);

    __shared__ float row[128];
    __shared__ float part[2];
    row[j] = pooled[(size_t)g * 128 + j] * scale;
    __syncthreads();
    float acc = fb1[j];
    const float* wr = fW1 + (size_t)j * 128;
#pragma unroll 8
    for (int k = 0; k < 128; ++k) acc += row[k] * wr[k];
    float v = fmaxf(acc, 0.0f) * fW2[j];
#pragma unroll
    for (int off = 32; off > 0; off >>= 1) v += __shfl_down(v, off);
    if ((j & 63) == 0) part[j >> 6] = v;
    __syncthreads();
    if (j == 0) out[g] = part[0] + part[1] + fb2[0];
}

extern "C" void kernel_launch(void* const* d_in, const int* in_sizes, int n_in,
                              void* d_out, int out_size, void* d_ws, size_t ws_size,
                              hipStream_t stream) {
    const float* x   = (const float*)d_in[0];
    const int*   ei  = (const int*)d_in[1];
    const float* ew  = (const float*)d_in[2];
    const int* batch = (const int*)d_in[3];
    const float* W1  = (const float*)d_in[4];
    const float* b1  = (const float*)d_in[5];
    const float* W2  = (const float*)d_in[6];
    const float* b2  = (const float*)d_in[7];
    const float* fW1 = (const float*)d_in[8];
    const float* fb1 = (const float*)d_in[9];
    const float* fW2 = (const float*)d_in[10];
    const float* fb2 = (const float*)d_in[11];
    float* out = (float*)d_out;

    const int N = in_sizes[0] / 128;
    const int E = in_sizes[2];
    const int G = out_size;
    const int* src = ei;
    const int* dst = ei + E;

    // workspace layout:
    unsigned short* A = (unsigned short*)d_ws;            // N*128 bf16, 4 planes of N*32
    unsigned short* B = A + (size_t)N * 128;              // N*128 bf16, 4 planes
    int2*  csr  = (int2*)(B + (size_t)N * 128);           // N*STRIDE entries (25.6 MB)
    int*   cnt  = (int*)(csr + (size_t)N * STRIDE);       // NREP*N
    float* dinv = (float*)(cnt + (size_t)NREP * N);       // N
    float* pooled = dinv + N;                             // G*128

    const int NB = (N + 7) / 8;

    // CSR build: zero counts -> bucket fill -> deg+compact+pad -> fold dinv[src]
    hipMemsetAsync(cnt, 0, (size_t)NREP * N * sizeof(int), stream);
    build_csr<<<(E + 255) / 256, 256, 0, stream>>>(src, dst, ew, cnt, csr, E, N);
    deg_compact<<<NB, 256, 0, stream>>>(cnt, csr, dinv, N);
    fold_dinv<<<NB, 256, 0, stream>>>(cnt, csr, dinv, N);

    // layer 1
    gemm_f32_nt<<<(N + 127) / 128, 256, 0, stream>>>(x, W1, A, N);
    aggregate_finalize<<<4 * NB, 256, 0, stream>>>(A, A, cnt, csr, dinv, b1, B, N, NB);

    // layer 2
    gemm_bf16_nt<<<(N + 127) / 128, 256, 0, stream>>>(B, W2, A, N);
    aggregate_finalize<<<4 * NB, 256, 0, stream>>>(A, A, cnt, csr, dinv, b2, B, N, NB);

    // pooling + head
    hipMemsetAsync(pooled, 0, (size_t)G * 128 * sizeof(float), stream);
    pool_partial<<<POOL_BLOCKS, 128, 0, stream>>>(B, batch, pooled, N);
    head_mlp<<<G, 128, 0, stream>>>(pooled, batch, N, fW1, fb1, fW2, fb2, out);
}

// Round 11
// 241.377 us; speedup vs baseline: 1.1909x; 1.1909x over previous
//
#include <hip/hip_runtime.h>
#include <hip/hip_bf16.h>

// GNN: 2x GCNConv(128->128) + ReLU, global_mean_pool, MLP head 128->128->1.
// R11: exact revert to R9 (best measured: 240.3 us). R10's feature-plane split
// regressed (agg 24->51 us): per-XCD L2s each need their own plane copy so
// fabric fill traffic didn't drop (FETCH unchanged), while per-edge instruction
// count and CSR traversal went 4x (VALUBusy 14->38%). Aggregate's ~24 us is an
// L2-miss-fabric floor: concurrency (R8) and cache partitioning (R10) both
// exhausted; the R7/R9 byte reductions were the real wins.

#define CAP 16            // slots per replica
#define NREP 4            // replicas
#define STRIDE 64         // entries per node (NREP*CAP)

typedef __attribute__((ext_vector_type(8))) short short8;
typedef __attribute__((ext_vector_type(4))) float floatx4;

__device__ inline unsigned short f2bf(float f) {
    unsigned int u = __float_as_uint(f);
    u += 0x7FFF + ((u >> 16) & 1);   // RNE
    return (unsigned short)(u >> 16);
}
__device__ inline float bf2f(unsigned short h) {
    return __uint_as_float(((unsigned int)h) << 16);
}

// ---------------- one-pass CSR build (4 replicas) ----------------
__global__ void build_csr(const int* __restrict__ src, const int* __restrict__ dst,
                          const float* __restrict__ ew,
                          int* __restrict__ cnt, int2* __restrict__ csr, int e, int n) {
    int i = blockIdx.x * blockDim.x + threadIdx.x;
    if (i < e) {
        int d = dst[i];
        int r = i & (NREP - 1);
        int pos = atomicAdd(&cnt[(size_t)r * n + d], 1);
        csr[((size_t)d << 6) + (r << 4) + pos] = make_int2(src[i], __float_as_int(ew[i]));
    }
}

// ---------------- weighted degree from buckets (32 lanes/node) ----------------
__global__ __launch_bounds__(256) void deg_from_csr(const int* __restrict__ cnt,
        const int2* __restrict__ csr, float* __restrict__ dinv, int n) {
    int node = blockIdx.x * 8 + (threadIdx.x >> 5);
    int lane = threadIdx.x & 31;
    float s = 0.0f;
    if (node < n) {
        int pos = lane & 15;
        int sa = lane >> 4;           // segs 0..1
        int sb = 2 + (lane >> 4);     // segs 2..3
        int ca = cnt[(size_t)sa * n + node];
        int cb = cnt[(size_t)sb * n + node];
        const int2* b = csr + ((size_t)node << 6);
        if (pos < ca) s += __int_as_float(b[lane].y);
        if (pos < cb) s += __int_as_float(b[32 + lane].y);
    }
#pragma unroll
    for (int off = 16; off > 0; off >>= 1) s += __shfl_down(s, off, 32);
    if (node < n && lane == 0) dinv[node] = rsqrtf(s + 1.0f);   // +1 self-loop
}

// ------- fold dinv[src] into weights + compact segments, store total count ----
__global__ __launch_bounds__(256) void fold_compact(int* __restrict__ cnt,
        int2* __restrict__ csr, const float* __restrict__ dinv, int n) {
    int node = blockIdx.x * 8 + (threadIdx.x >> 5);
    if (node >= n) return;
    int lane = threadIdx.x & 31;
    int c0 = cnt[node];
    int c1 = cnt[(size_t)1 * n + node];
    int c2 = cnt[(size_t)2 * n + node];
    int c3 = cnt[(size_t)3 * n + node];
    int pre[4] = {0, c0, c0 + c1, c0 + c1 + c2};
    int cs[4] = {c0, c1, c2, c3};

    int2* b = csr + ((size_t)node << 6);
    int pos = lane & 15;
    int sa = lane >> 4;
    int sb = 2 + (lane >> 4);
    bool va = pos < cs[sa];
    bool vb = pos < cs[sb];
    int2 ea = va ? b[lane] : make_int2(0, 0);
    int2 eb = vb ? b[32 + lane] : make_int2(0, 0);
    if (va) ea.y = __float_as_int(__int_as_float(ea.y) * dinv[ea.x]);
    if (vb) eb.y = __float_as_int(__int_as_float(eb.y) * dinv[eb.x]);
    if (va) b[pre[sa] + pos] = ea;
    if (vb) b[pre[sb] + pos] = eb;
    if (lane == 0) cnt[node] = c0 + c1 + c2 + c3;
}

// ------- split-bf16 MFMA GEMM (fp32 input): C = X @ W^T, C bf16 -------
#define PW 136
__global__ __launch_bounds__(256) void gemm_f32_nt(const float* __restrict__ X,
        const float* __restrict__ W, unsigned short* __restrict__ C, int M) {
    __shared__ unsigned short whi[128 * PW];
    __shared__ unsigned short wlo[128 * PW];
    const int t = threadIdx.x;

    {
        int j = t >> 1;
        int c0 = (t & 1) * 64;
        const floatx4* wr = (const floatx4*)(W + (size_t)j * 128 + c0);
        unsigned short* dh = &whi[j * PW + c0];
        unsigned short* dl = &wlo[j * PW + c0];
#pragma unroll
        for (int i = 0; i < 16; ++i) {
            floatx4 v = wr[i];
            ushort4 hv, lv;
            hv.x = f2bf(v.x); lv.x = f2bf(v.x - bf2f(hv.x));
            hv.y = f2bf(v.y); lv.y = f2bf(v.y - bf2f(hv.y));
            hv.z = f2bf(v.z); lv.z = f2bf(v.z - bf2f(hv.z));
            hv.w = f2bf(v.w); lv.w = f2bf(v.w - bf2f(hv.w));
            *(ushort4*)(dh + i * 4) = hv;
            *(ushort4*)(dl + i * 4) = lv;
        }
    }
    __syncthreads();

    const int wave = t >> 6;
    const int lane = t & 63;
    const int q = lane >> 4;
    const int ln = lane & 15;
    const int rowbase = blockIdx.x * 128 + wave * 32;

    floatx4 acc[2][8];
#pragma unroll
    for (int s = 0; s < 2; ++s)
#pragma unroll
        for (int ct = 0; ct < 8; ++ct) acc[s][ct] = (floatx4){0.f, 0.f, 0.f, 0.f};

#pragma unroll
    for (int ks = 0; ks < 4; ++ks) {
        short8 ahi[2], alo[2];
#pragma unroll
        for (int s = 0; s < 2; ++s) {
            int row = rowbase + s * 16 + ln;
            int rowc = (row < M) ? row : (M - 1);
            const floatx4* xr = (const floatx4*)(X + (size_t)rowc * 128 + ks * 32 + q * 8);
            floatx4 x0 = xr[0];
            floatx4 x1 = xr[1];
            unsigned short h, l;
            h = f2bf(x0.x); l = f2bf(x0.x - bf2f(h)); ahi[s][0] = (short)h; alo[s][0] = (short)l;
            h = f2bf(x0.y); l = f2bf(x0.y - bf2f(h)); ahi[s][1] = (short)h; alo[s][1] = (short)l;
            h = f2bf(x0.z); l = f2bf(x0.z - bf2f(h)); ahi[s][2] = (short)h; alo[s][2] = (short)l;
            h = f2bf(x0.w); l = f2bf(x0.w - bf2f(h)); ahi[s][3] = (short)h; alo[s][3] = (short)l;
            h = f2bf(x1.x); l = f2bf(x1.x - bf2f(h)); ahi[s][4] = (short)h; alo[s][4] = (short)l;
            h = f2bf(x1.y); l = f2bf(x1.y - bf2f(h)); ahi[s][5] = (short)h; alo[s][5] = (short)l;
            h = f2bf(x1.z); l = f2bf(x1.z - bf2f(h)); ahi[s][6] = (short)h; alo[s][6] = (short)l;
            h = f2bf(x1.w); l = f2bf(x1.w - bf2f(h)); ahi[s][7] = (short)h; alo[s][7] = (short)l;
        }
#pragma unroll
        for (int ct = 0; ct < 8; ++ct) {
            int lidx = (ct * 16 + ln) * PW + ks * 32 + q * 8;
            short8 bhi = *(const short8*)&whi[lidx];
            short8 blo = *(const short8*)&wlo[lidx];
#pragma unroll
            for (int s = 0; s < 2; ++s) {
                acc[s][ct] = __builtin_amdgcn_mfma_f32_16x16x32_bf16(ahi[s], bhi, acc[s][ct], 0, 0, 0);
                acc[s][ct] = __builtin_amdgcn_mfma_f32_16x16x32_bf16(ahi[s], blo, acc[s][ct], 0, 0, 0);
                acc[s][ct] = __builtin_amdgcn_mfma_f32_16x16x32_bf16(alo[s], bhi, acc[s][ct], 0, 0, 0);
            }
        }
    }

#pragma unroll
    for (int s = 0; s < 2; ++s) {
#pragma unroll
        for (int r = 0; r < 4; ++r) {
            int row = rowbase + s * 16 + q * 4 + r;
            if (row < M) {
                unsigned short* cr = C + (size_t)row * 128 + ln;
#pragma unroll
                for (int ct = 0; ct < 8; ++ct) cr[ct * 16] = f2bf(acc[s][ct][r]);
            }
        }
    }
}

// ------- bf16-input MFMA GEMM: C = X @ W^T, X bf16, W split hi/lo, C bf16 ----
__global__ __launch_bounds__(256) void gemm_bf16_nt(const unsigned short* __restrict__ X,
        const float* __restrict__ W, unsigned short* __restrict__ C, int M) {
    __shared__ unsigned short whi[128 * PW];
    __shared__ unsigned short wlo[128 * PW];
    const int t = threadIdx.x;

    {
        int j = t >> 1;
        int c0 = (t & 1) * 64;
        const floatx4* wr = (const floatx4*)(W + (size_t)j * 128 + c0);
        unsigned short* dh = &whi[j * PW + c0];
        unsigned short* dl = &wlo[j * PW + c0];
#pragma unroll
        for (int i = 0; i < 16; ++i) {
            floatx4 v = wr[i];
            ushort4 hv, lv;
            hv.x = f2bf(v.x); lv.x = f2bf(v.x - bf2f(hv.x));
            hv.y = f2bf(v.y); lv.y = f2bf(v.y - bf2f(hv.y));
            hv.z = f2bf(v.z); lv.z = f2bf(v.z - bf2f(hv.z));
            hv.w = f2bf(v.w); lv.w = f2bf(v.w - bf2f(hv.w));
            *(ushort4*)(dh + i * 4) = hv;
            *(ushort4*)(dl + i * 4) = lv;
        }
    }
    __syncthreads();

    const int wave = t >> 6;
    const int lane = t & 63;
    const int q = lane >> 4;
    const int ln = lane & 15;
    const int rowbase = blockIdx.x * 128 + wave * 32;

    floatx4 acc[2][8];
#pragma unroll
    for (int s = 0; s < 2; ++s)
#pragma unroll
        for (int ct = 0; ct < 8; ++ct) acc[s][ct] = (floatx4){0.f, 0.f, 0.f, 0.f};

#pragma unroll
    for (int ks = 0; ks < 4; ++ks) {
        short8 a[2];
#pragma unroll
        for (int s = 0; s < 2; ++s) {
            int row = rowbase + s * 16 + ln;
            int rowc = (row < M) ? row : (M - 1);
            a[s] = *(const short8*)(X + (size_t)rowc * 128 + ks * 32 + q * 8);
        }
#pragma unroll
        for (int ct = 0; ct < 8; ++ct) {
            int lidx = (ct * 16 + ln) * PW + ks * 32 + q * 8;
            short8 bhi = *(const short8*)&whi[lidx];
            short8 blo = *(const short8*)&wlo[lidx];
#pragma unroll
            for (int s = 0; s < 2; ++s) {
                acc[s][ct] = __builtin_amdgcn_mfma_f32_16x16x32_bf16(a[s], bhi, acc[s][ct], 0, 0, 0);
                acc[s][ct] = __builtin_amdgcn_mfma_f32_16x16x32_bf16(a[s], blo, acc[s][ct], 0, 0, 0);
            }
        }
    }

#pragma unroll
    for (int s = 0; s < 2; ++s) {
#pragma unroll
        for (int r = 0; r < 4; ++r) {
            int row = rowbase + s * 16 + q * 4 + r;
            if (row < M) {
                unsigned short* cr = C + (size_t)row * 128 + ln;
#pragma unroll
                for (int ct = 0; ct < 8; ++ct) cr[ct * 16] = f2bf(acc[s][ct][r]);
            }
        }
    }
}

// ------ aggregate + finalize (bf16 messages, bf16 output, 4-deep) ------
// B[d] = relu( di * sum_in(w*h[s]) + hlin[d]*di^2 + bias ),  w = ew*dinv[s]
__global__ __launch_bounds__(256) void aggregate_finalize(
        const unsigned short* __restrict__ h, const unsigned short* __restrict__ hlin,
        const int* __restrict__ cnt, const int2* __restrict__ csr,
        const float* __restrict__ dinv, const float* __restrict__ bias,
        unsigned short* __restrict__ outb, int n) {
    int node = blockIdx.x * 8 + (threadIdx.x >> 5);
    if (node >= n) return;
    int lane = threadIdx.x & 31;
    float di = dinv[node];
    float sl = di * di;
    float4 b4 = ((const float4*)bias)[lane];
    ushort4 bse = ((const ushort4*)(hlin + (size_t)node * 128))[lane];
    float4 acc = make_float4(0.f, 0.f, 0.f, 0.f);

    const int2* b = csr + ((size_t)node << 6);
    const int4* bv = (const int4*)b;     // 16B-aligned (node*512)
    int c = cnt[node];
    int k = 0;
    for (; k + 4 <= c; k += 4) {
        int4 ea = bv[k >> 1];
        int4 eb = bv[(k >> 1) + 1];
        float w0 = __int_as_float(ea.y);
        float w1 = __int_as_float(ea.w);
        float w2 = __int_as_float(eb.y);
        float w3 = __int_as_float(eb.w);
        ushort4 h0 = ((const ushort4*)(h + (size_t)ea.x * 128))[lane];
        ushort4 h1 = ((const ushort4*)(h + (size_t)ea.z * 128))[lane];
        ushort4 h2 = ((const ushort4*)(h + (size_t)eb.x * 128))[lane];
        ushort4 h3 = ((const ushort4*)(h + (size_t)eb.z * 128))[lane];
        acc.x += bf2f(h0.x) * w0 + bf2f(h1.x) * w1 + bf2f(h2.x) * w2 + bf2f(h3.x) * w3;
        acc.y += bf2f(h0.y) * w0 + bf2f(h1.y) * w1 + bf2f(h2.y) * w2 + bf2f(h3.y) * w3;
        acc.z += bf2f(h0.z) * w0 + bf2f(h1.z) * w1 + bf2f(h2.z) * w2 + bf2f(h3.z) * w3;
        acc.w += bf2f(h0.w) * w0 + bf2f(h1.w) * w1 + bf2f(h2.w) * w2 + bf2f(h3.w) * w3;
    }
    if (k + 2 <= c) {
        int4 ea = bv[k >> 1];
        float w0 = __int_as_float(ea.y);
        float w1 = __int_as_float(ea.w);
        ushort4 h0 = ((const ushort4*)(h + (size_t)ea.x * 128))[lane];
        ushort4 h1 = ((const ushort4*)(h + (size_t)ea.z * 128))[lane];
        acc.x += bf2f(h0.x) * w0 + bf2f(h1.x) * w1;
        acc.y += bf2f(h0.y) * w0 + bf2f(h1.y) * w1;
        acc.z += bf2f(h0.z) * w0 + bf2f(h1.z) * w1;
        acc.w += bf2f(h0.w) * w0 + bf2f(h1.w) * w1;
        k += 2;
    }
    if (k < c) {
        int2 ed = b[k];
        float w = __int_as_float(ed.y);
        ushort4 hv = ((const ushort4*)(h + (size_t)ed.x * 128))[lane];
        acc.x += bf2f(hv.x) * w;
        acc.y += bf2f(hv.y) * w;
        acc.z += bf2f(hv.z) * w;
        acc.w += bf2f(hv.w) * w;
    }
    ushort4 o;
    o.x = f2bf(fmaxf(acc.x * di + bf2f(bse.x) * sl + b4.x, 0.0f));
    o.y = f2bf(fmaxf(acc.y * di + bf2f(bse.y) * sl + b4.y, 0.0f));
    o.z = f2bf(fmaxf(acc.z * di + bf2f(bse.z) * sl + b4.z, 0.0f));
    o.w = f2bf(fmaxf(acc.w * di + bf2f(bse.w) * sl + b4.w, 0.0f));
    ((ushort4*)(outb + (size_t)node * 128))[lane] = o;
}

// ---------------- pooling: partial sums (bf16 input), boundary-flush ----------
#define POOL_BLOCKS 1024
__global__ __launch_bounds__(128) void pool_partial(const unsigned short* __restrict__ h,
        const int* __restrict__ batch, float* __restrict__ pooled, int n) {
    int chunk = (n + POOL_BLOCKS - 1) / POOL_BLOCKS;
    int s = blockIdx.x * chunk;
    if (s >= n) return;
    int e = min(s + chunk, n);
    int j = threadIdx.x;
    int curg = batch[s];
    float sum = 0.0f;
    for (int i = s; i < e; ++i) {
        int g = batch[i];
        if (g != curg) {
            atomicAdd(&pooled[(size_t)curg * 128 + j], sum);
            sum = 0.0f;
            curg = g;
        }
        sum += bf2f(h[(size_t)i * 128 + j]);
    }
    atomicAdd(&pooled[(size_t)curg * 128 + j], sum);
}

// ---------------- head MLP ----------------
__global__ __launch_bounds__(128) void head_mlp(const float* __restrict__ pooled,
        const int* __restrict__ batch, int n,
        const float* __restrict__ fW1, const float* __restrict__ fb1,
        const float* __restrict__ fW2, const float* __restrict__ fb2,
        float* __restrict__ out) {
    int g = blockIdx.x;
    int j = threadIdx.x;
    int lo = 0, hi = n;
    while (lo < hi) { int mid = (lo + hi) >> 1; if (batch[mid] < g) lo = mid + 1; else hi = mid; }
    int s = lo;
    hi = n;
    while (lo < hi) { int mid = (lo + hi) >> 1; if (batch[mid] < g + 1) lo = mid + 1; else hi = mid; }
    int cnt = lo - s;
    float scale = 1.0f / fmaxf((float)cnt, 1.0f);

    __shared__ float row[128];
    __shared__ float part[2];
    row[j] = pooled[(size_t)g * 128 + j] * scale;
    __syncthreads();
    float acc = fb1[j];
    const float* wr = fW1 + (size_t)j * 128;
#pragma unroll 8
    for (int k = 0; k < 128; ++k) acc += row[k] * wr[k];
    float v = fmaxf(acc, 0.0f) * fW2[j];
#pragma unroll
    for (int off = 32; off > 0; off >>= 1) v += __shfl_down(v, off);
    if ((j & 63) == 0) part[j >> 6] = v;
    __syncthreads();
    if (j == 0) out[g] = part[0] + part[1] + fb2[0];
}

extern "C" void kernel_launch(void* const* d_in, const int* in_sizes, int n_in,
                              void* d_out, int out_size, void* d_ws, size_t ws_size,
                              hipStream_t stream) {
    const float* x   = (const float*)d_in[0];
    const int*   ei  = (const int*)d_in[1];
    const float* ew  = (const float*)d_in[2];
    const int* batch = (const int*)d_in[3];
    const float* W1  = (const float*)d_in[4];
    const float* b1  = (const float*)d_in[5];
    const float* W2  = (const float*)d_in[6];
    const float* b2  = (const float*)d_in[7];
    const float* fW1 = (const float*)d_in[8];
    const float* fb1 = (const float*)d_in[9];
    const float* fW2 = (const float*)d_in[10];
    const float* fb2 = (const float*)d_in[11];
    float* out = (float*)d_out;

    const int N = in_sizes[0] / 128;
    const int E = in_sizes[2];
    const int G = out_size;
    const int* src = ei;
    const int* dst = ei + E;

    // workspace layout:
    unsigned short* A = (unsigned short*)d_ws;            // N*128 bf16 (12.8 MB)
    unsigned short* B = A + (size_t)N * 128;              // N*128 bf16 (12.8 MB)
    int2*  csr  = (int2*)(B + (size_t)N * 128);           // N*STRIDE entries (25.6 MB)
    int*   cnt  = (int*)(csr + (size_t)N * STRIDE);       // NREP*N
    float* dinv = (float*)(cnt + (size_t)NREP * N);       // N
    float* pooled = dinv + N;                             // G*128

    // CSR build: zero counts -> one-pass bucket fill -> degree -> fold+compact
    hipMemsetAsync(cnt, 0, (size_t)NREP * N * sizeof(int), stream);
    build_csr<<<(E + 255) / 256, 256, 0, stream>>>(src, dst, ew, cnt, csr, E, N);
    deg_from_csr<<<(N + 7) / 8, 256, 0, stream>>>(cnt, csr, dinv, N);
    fold_compact<<<(N + 7) / 8, 256, 0, stream>>>(cnt, csr, dinv, N);

    // layer 1
    gemm_f32_nt<<<(N + 127) / 128, 256, 0, stream>>>(x, W1, A, N);
    aggregate_finalize<<<(N + 7) / 8, 256, 0, stream>>>(A, A, cnt, csr, dinv, b1, B, N);

    // layer 2
    gemm_bf16_nt<<<(N + 127) / 128, 256, 0, stream>>>(B, W2, A, N);
    aggregate_finalize<<<(N + 7) / 8, 256, 0, stream>>>(A, A, cnt, csr, dinv, b2, B, N);

    // pooling + head
    hipMemsetAsync(pooled, 0, (size_t)G * 128 * sizeof(float), stream);
    pool_partial<<<POOL_BLOCKS, 128, 0, stream>>>(B, batch, pooled, N);
    head_mlp<<<G, 128, 0, stream>>>(pooled, batch, N, fW1, fb1, fW2, fb2, out);
}